// Round 7
// baseline (179.865 us; speedup 1.0000x reference)
//
#include <hip/hip_runtime.h>

#define Bx 16
#define Cx 64
#define Lx 512
#define Dx 768
#define NPx 68   // int((512+16)/8 + 2)
#define PER 7
#define ROW4 (NPx * (Dx / 4))  // 13056 float4 per (b,c) row

// ws layout (floats): m[8192] | WS[112] | WRI[112] | p[786432]
#define WS_OFF 8192
#define WRI_OFF 8304
#define P_OFF 8416

// ---- Kernel A: blocks 0..31: m[b,l] = mean_c/sqrt(var_c);  block 32:
//      per-phase weight sums WS[j][p] (all l), WRI[j][p] (interior l). ----
__global__ __launch_bounds__(256) void prep_kernel(
    const float* __restrict__ x, const float* __restrict__ w_s,
    const float* __restrict__ w_r, float* __restrict__ ws) {
    int bid = blockIdx.x, tid = threadIdx.x;
    if (bid < 32) {
        int idx = bid * 256 + tid;  // b*Lx + l
        int b = idx >> 9, l = idx & 511;
        const float* xp = x + (size_t)b * Cx * Lx + l;
        float s = 0.f, ss = 0.f;
#pragma unroll 8
        for (int c = 0; c < Cx; ++c) {
            float v = xp[(size_t)c * Lx];
            s += v;
            ss += v * v;
        }
        float mean = s / (float)Cx;
        float var = (ss - s * s / (float)Cx) / (float)(Cx - 1);
        ws[idx] = mean * rsqrtf(var);
    } else if (tid < 224) {
        int sel = tid >= 112;            // 0: WS (w_s, all l), 1: WRI (w_r, int.)
        int t = tid - sel * 112;
        int j = t / PER, p = t - (t / PER) * PER;
        const float* w = (sel ? w_r : w_s) + (size_t)j * Lx;
        float sum = 0.f;
        if (!sel) {
            for (int l = p; l < Lx; l += PER) sum += w[l];
        } else {
            int l0 = p + 7 * ((3 - p + 6) / 7);  // first l>=3 with l%7==p
            for (int l = l0; l <= Lx - 4; l += PER) sum += w[l];
        }
        ws[(sel ? WRI_OFF : WS_OFF) + j * PER + p] = sum;
    }
}

// ---- Kernel B: per-(b,c) decompose + projections -> p[bc][768] in ws ----
__global__ __launch_bounds__(256) void token_kernel(
    const float* __restrict__ x, const float* __restrict__ gamma,
    const float* __restrict__ beta, const float* __restrict__ ws,
    const float* __restrict__ w_t, const float* __restrict__ b_t,
    const float* __restrict__ b_s,
    const float* __restrict__ w_r, const float* __restrict__ b_r,
    const float* __restrict__ w_g, const float* __restrict__ b_g,
    float* __restrict__ p) {
    __shared__ __align__(16) float s_xt[Lx];
    __shared__ __align__(16) float s_tr[Lx];
    __shared__ __align__(16) float s_det[Lx];
    __shared__ float s_ph[PER];
    __shared__ __align__(16) float s_cat[48];

    const int bc = blockIdx.x;
    const int b = bc >> 6;
    const int tid = threadIdx.x;

    const float* xp = x + (size_t)bc * Lx;
    const float* gp = gamma + (size_t)bc * Lx;
    const float* bp = beta + (size_t)bc * Lx;
    const float* mp = ws + (size_t)b * Lx;

    // 1. xt = gamma*(x - m) + beta
#pragma unroll
    for (int u = 0; u < 2; ++u) {
        int l = tid + u * 256;
        s_xt[l] = gp[l] * (xp[l] - mp[l]) + bp[l];
    }
    __syncthreads();

    // 2. trend (7-pt centered MA) + det on interior (0 at edges)
#pragma unroll
    for (int u = 0; u < 2; ++u) {
        int l = tid + u * 256;
        float t = 0.f, d = 0.f;
        if (l >= 3 && l <= Lx - 4) {
#pragma unroll
            for (int k = -3; k <= 3; ++k) t += s_xt[l + k];
            t *= (1.f / 7.f);
            d = s_xt[l] - t;
        }
        s_tr[l] = t;
        s_det[l] = d;
    }
    __syncthreads();

    // 3. raw per-phase averages (demeaned later, locally)
    if (tid < 224) {
        int ph = tid >> 5, j = tid & 31;
        int l0 = ph + 7 * ((3 - ph + 6) / 7);
        int cnt = (Lx - 4 - l0) / 7 + 1;
        float sum = 0.f;
#pragma unroll
        for (int k = 0; k < 3; ++k) {
            int idx = j + 32 * k;
            if (idx < cnt) sum += s_det[l0 + 7 * idx];  // stride-7: bank-free
        }
#pragma unroll
        for (int off = 16; off >= 1; off >>= 1) sum += __shfl_xor(sum, off);
        if (j == 0) s_ph[ph] = sum / (float)cnt;
    }
    __syncthreads();

    // 4. cat[48]: trend-dot (512), seasonal (7-term via WS), resid-dot
    //    (512 via det, minus 7-term via WRI)
    if (tid < 192) {
        int j = tid >> 2, q = tid & 3;
        float ph[PER], mn = 0.f;
#pragma unroll
        for (int k = 0; k < PER; ++k) {
            ph[k] = s_ph[k];
            mn += ph[k];
        }
        mn *= (1.f / 7.f);
        float acc = 0.f, bias = 0.f;
        if (j < 16 || j >= 32) {
            const float* stream = (j < 16) ? s_tr : s_det;
            const float* w = (j < 16) ? w_t : w_r;
            int jj = (j < 16) ? j : j - 32;
            const float4* wr =
                reinterpret_cast<const float4*>(w + (size_t)jj * Lx + q * 128);
            const float4* sp = reinterpret_cast<const float4*>(stream + q * 128);
#pragma unroll 8
            for (int i = 0; i < 32; ++i) {
                float4 a = sp[i], wv = wr[i];
                acc += a.x * wv.x + a.y * wv.y + a.z * wv.z + a.w * wv.w;
            }
            if (q == 0) {
                bias = (j < 16) ? b_t[jj] : b_r[jj];
                if (j >= 32) {
                    const float* wri = ws + WRI_OFF + jj * PER;
#pragma unroll
                    for (int k = 0; k < PER; ++k)
                        acc -= (ph[k] - mn) * wri[k];
                }
            }
        } else if (q == 0) {
            int jj = j - 16;
            const float* wsp = ws + WS_OFF + jj * PER;
#pragma unroll
            for (int k = 0; k < PER; ++k) acc += (ph[k] - mn) * wsp[k];
            bias = b_s[jj];
        }
        acc += __shfl_xor(acc, 1);
        acc += __shfl_xor(acc, 2);
        if (q == 0) s_cat[j] = acc + bias;
    }
    __syncthreads();

    // 5. p[bc][768] = cat @ w_g.T + b_g
    {
        const float4* c4 = reinterpret_cast<const float4*>(s_cat);
        float* prow = p + (size_t)bc * Dx;
#pragma unroll
        for (int u = 0; u < 3; ++u) {
            int d = tid + u * 256;
            const float4* wg4 =
                reinterpret_cast<const float4*>(w_g + (size_t)d * 48);
            float acc = 0.f;
#pragma unroll
            for (int kk = 0; kk < 12; ++kk) {
                float4 w4 = wg4[kk], cc = c4[kk];
                acc += w4.x * cc.x + w4.y * cc.y + w4.z * cc.z + w4.w * cc.w;
            }
            prow[d] = acc + b_g[d];
        }
    }
}

// ---- Kernel C (DIAGNOSTIC): register-sourced broadcast, writes the full
//      output REPS times (idempotent; last pass leaves correct values).
//      Purpose: push this dispatch into rocprof's top-5 so we finally see
//      FETCH_SIZE / WRITE_SIZE / hbm_gbps for OUR store pattern. ----
#define REPS 4
__global__ __launch_bounds__(192) void bcast_diag_kernel(
    const float4* __restrict__ p4, float4* __restrict__ out4) {
    int bc = blockIdx.x;     // 1024
    int tid = threadIdx.x;   // 0..191
    float4 v = p4[bc * 192 + tid];
    float4* row = out4 + (size_t)bc * ROW4 + tid;
#pragma unroll 1
    for (int rep = 0; rep < REPS; ++rep) {
#pragma unroll 4
        for (int n = 0; n < NPx; ++n) row[(size_t)n * 192] = v;
    }
}

extern "C" void kernel_launch(void* const* d_in, const int* in_sizes, int n_in,
                              void* d_out, int out_size, void* d_ws,
                              size_t ws_size, hipStream_t stream) {
    const float* data_x = (const float*)d_in[0];
    // d_in[1] = data_y (unused by the reference)
    const float* gamma = (const float*)d_in[2];
    const float* beta = (const float*)d_in[3];
    const float* w_t = (const float*)d_in[4];
    const float* b_t = (const float*)d_in[5];
    const float* w_s = (const float*)d_in[6];
    const float* b_s = (const float*)d_in[7];
    const float* w_r = (const float*)d_in[8];
    const float* b_r = (const float*)d_in[9];
    const float* w_g = (const float*)d_in[10];
    const float* b_g = (const float*)d_in[11];
    float* out = (float*)d_out;
    float* ws = (float*)d_ws;
    float* p = ws + P_OFF;

    prep_kernel<<<33, 256, 0, stream>>>(data_x, w_s, w_r, ws);

    token_kernel<<<Bx * Cx, 256, 0, stream>>>(data_x, gamma, beta, ws, w_t,
                                              b_t, b_s, w_r, b_r, w_g, b_g, p);

    bcast_diag_kernel<<<Bx * Cx, 192, 0, stream>>>(
        reinterpret_cast<const float4*>(p), reinterpret_cast<float4*>(out));
}

// Round 8
// 82.374 us; speedup vs baseline: 2.1835x; 2.1835x over previous
//
#include <hip/hip_runtime.h>

#define Bx 16
#define Cx 64
#define Lx 512
#define Dx 768
#define NPx 68   // int((512+16)/8 + 2)
#define PER 7
#define ROW4 (NPx * (Dx / 4))  // 13056 float4 per (b,c) row

// ws layout (floats): m[8192] | WS[112] | WRI[112]
#define WS_OFF 8192
#define WRI_OFF 8304

// ---- Kernel A: blocks 0..31: m[b,l] = mean_c/sqrt(var_c);  block 32:
//      per-phase weight sums WS[j][p] (w_s, all l), WRI[j][p] (w_r, interior).
__global__ __launch_bounds__(256) void prep_kernel(
    const float* __restrict__ x, const float* __restrict__ w_s,
    const float* __restrict__ w_r, float* __restrict__ ws) {
    int bid = blockIdx.x, tid = threadIdx.x;
    if (bid < 32) {
        int idx = bid * 256 + tid;  // b*Lx + l
        int b = idx >> 9, l = idx & 511;
        const float* xp = x + (size_t)b * Cx * Lx + l;
        float s = 0.f, ss = 0.f;
#pragma unroll 8
        for (int c = 0; c < Cx; ++c) {
            float v = xp[(size_t)c * Lx];
            s += v;
            ss += v * v;
        }
        float mean = s / (float)Cx;
        float var = (ss - s * s / (float)Cx) / (float)(Cx - 1);
        ws[idx] = mean * rsqrtf(var);
    } else if (tid < 224) {
        int sel = tid >= 112;            // 0: WS (w_s, all l), 1: WRI (w_r, int.)
        int t = tid - sel * 112;
        int j = t / PER, p = t - (t / PER) * PER;
        const float* w = (sel ? w_r : w_s) + (size_t)j * Lx;
        float sum = 0.f;
        if (!sel) {
            for (int l = p; l < Lx; l += PER) sum += w[l];
        } else {
            int l0 = p + 7 * ((3 - p + 6) / 7);  // first l>=3 with l%7==p
            for (int l = l0; l <= Lx - 4; l += PER) sum += w[l];
        }
        ws[(sel ? WRI_OFF : WS_OFF) + j * PER + p] = sum;
    }
}

// ---- Kernel B: fused per-(b,c) decompose + projections + 68-slot store ----
__global__ __launch_bounds__(256) void fused_kernel(
    const float* __restrict__ x, const float* __restrict__ gamma,
    const float* __restrict__ beta, const float* __restrict__ ws,
    const float* __restrict__ w_t, const float* __restrict__ b_t,
    const float* __restrict__ b_s,
    const float* __restrict__ w_r, const float* __restrict__ b_r,
    const float* __restrict__ w_g, const float* __restrict__ b_g,
    float* __restrict__ out) {
    __shared__ __align__(16) float s_xt[Lx];
    __shared__ __align__(16) float s_tr[Lx];
    __shared__ __align__(16) float s_det[Lx];
    __shared__ float s_ph[PER];
    __shared__ __align__(16) float s_cat[48];
    __shared__ __align__(16) float s_p[Dx];

    const int bc = blockIdx.x;
    const int b = bc >> 6;
    const int tid = threadIdx.x;

    const float* xp = x + (size_t)bc * Lx;
    const float* gp = gamma + (size_t)bc * Lx;
    const float* bp = beta + (size_t)bc * Lx;
    const float* mp = ws + (size_t)b * Lx;

    // A. xt = gamma*(x - m) + beta
#pragma unroll
    for (int u = 0; u < 2; ++u) {
        int l = tid + u * 256;
        s_xt[l] = gp[l] * (xp[l] - mp[l]) + bp[l];
    }
    __syncthreads();

    // B. trend (7-pt centered MA) + det on interior (0 at edges)
#pragma unroll
    for (int u = 0; u < 2; ++u) {
        int l = tid + u * 256;
        float t = 0.f, d = 0.f;
        if (l >= 3 && l <= Lx - 4) {
#pragma unroll
            for (int k = -3; k <= 3; ++k) t += s_xt[l + k];
            t *= (1.f / 7.f);
            d = s_xt[l] - t;
        }
        s_tr[l] = t;
        s_det[l] = d;
    }
    __syncthreads();

    // C. raw per-phase averages (demeaned locally in phase D)
    if (tid < 224) {
        int ph = tid >> 5, j = tid & 31;
        int l0 = ph + 7 * ((3 - ph + 6) / 7);
        int cnt = (Lx - 4 - l0) / 7 + 1;
        float sum = 0.f;
#pragma unroll
        for (int k = 0; k < 3; ++k) {
            int idx = j + 32 * k;
            if (idx < cnt) sum += s_det[l0 + 7 * idx];  // stride-7: bank-free
        }
#pragma unroll
        for (int off = 16; off >= 1; off >>= 1) sum += __shfl_xor(sum, off);
        if (j == 0) s_ph[ph] = sum / (float)cnt;
    }
    __syncthreads();

    // D. cat[48]: trend-dot (512), seasonal (7-term via WS), resid-dot
    //    (512 via det, minus 7-term via WRI)
    if (tid < 192) {
        int j = tid >> 2, q = tid & 3;
        float ph[PER], mn = 0.f;
#pragma unroll
        for (int k = 0; k < PER; ++k) {
            ph[k] = s_ph[k];
            mn += ph[k];
        }
        mn *= (1.f / 7.f);
        float acc = 0.f, bias = 0.f;
        if (j < 16 || j >= 32) {
            const float* stream = (j < 16) ? s_tr : s_det;
            const float* w = (j < 16) ? w_t : w_r;
            int jj = (j < 16) ? j : j - 32;
            const float4* wr =
                reinterpret_cast<const float4*>(w + (size_t)jj * Lx + q * 128);
            const float4* sp = reinterpret_cast<const float4*>(stream + q * 128);
#pragma unroll 8
            for (int i = 0; i < 32; ++i) {
                float4 a = sp[i], wv = wr[i];
                acc += a.x * wv.x + a.y * wv.y + a.z * wv.z + a.w * wv.w;
            }
            if (q == 0) {
                bias = (j < 16) ? b_t[jj] : b_r[jj];
                if (j >= 32) {
                    const float* wri = ws + WRI_OFF + jj * PER;
#pragma unroll
                    for (int k = 0; k < PER; ++k)
                        acc -= (ph[k] - mn) * wri[k];
                }
            }
        } else if (q == 0) {
            int jj = j - 16;
            const float* wsp = ws + WS_OFF + jj * PER;
#pragma unroll
            for (int k = 0; k < PER; ++k) acc += (ph[k] - mn) * wsp[k];
            bias = b_s[jj];
        }
        acc += __shfl_xor(acc, 1);
        acc += __shfl_xor(acc, 2);
        if (q == 0) s_cat[j] = acc + bias;
    }
    __syncthreads();

    // E. p[768] = cat @ w_g.T + b_g -> LDS
    {
        const float4* c4 = reinterpret_cast<const float4*>(s_cat);
#pragma unroll
        for (int u = 0; u < 3; ++u) {
            int d = tid + u * 256;
            const float4* wg4 =
                reinterpret_cast<const float4*>(w_g + (size_t)d * 48);
            float acc = 0.f;
#pragma unroll
            for (int kk = 0; kk < 12; ++kk) {
                float4 w4 = wg4[kk], cc = c4[kk];
                acc += w4.x * cc.x + w4.y * cc.y + w4.z * cc.z + w4.w * cc.w;
            }
            s_p[d] = acc + b_g[d];
        }
    }
    __syncthreads();

    // F. store: ALL 256 threads. Row has 13056 float4 = 51 per thread.
    //    d4(k) = (tid + 256k) mod 192 cycles with period 3 (256 = 192+64),
    //    so each thread needs only 3 register float4s.
    {
        const float4* p4 = reinterpret_cast<const float4*>(s_p);
        int r0 = tid < 192 ? tid : tid - 192;
        int r1 = r0 + 64;  if (r1 >= 192) r1 -= 192;
        int r2 = r1 + 64;  if (r2 >= 192) r2 -= 192;
        float4 v0 = p4[r0], v1 = p4[r1], v2 = p4[r2];
        float4* row = reinterpret_cast<float4*>(out) + (size_t)bc * ROW4 + tid;
#pragma unroll
        for (int k = 0; k < 51; k += 3) {
            row[(size_t)k * 256] = v0;
            row[(size_t)(k + 1) * 256] = v1;
            row[(size_t)(k + 2) * 256] = v2;
        }
    }
}

extern "C" void kernel_launch(void* const* d_in, const int* in_sizes, int n_in,
                              void* d_out, int out_size, void* d_ws,
                              size_t ws_size, hipStream_t stream) {
    const float* data_x = (const float*)d_in[0];
    // d_in[1] = data_y (unused by the reference)
    const float* gamma = (const float*)d_in[2];
    const float* beta = (const float*)d_in[3];
    const float* w_t = (const float*)d_in[4];
    const float* b_t = (const float*)d_in[5];
    const float* w_s = (const float*)d_in[6];
    const float* b_s = (const float*)d_in[7];
    const float* w_r = (const float*)d_in[8];
    const float* b_r = (const float*)d_in[9];
    const float* w_g = (const float*)d_in[10];
    const float* b_g = (const float*)d_in[11];
    float* out = (float*)d_out;
    float* ws = (float*)d_ws;

    prep_kernel<<<33, 256, 0, stream>>>(data_x, w_s, w_r, ws);

    fused_kernel<<<Bx * Cx, 256, 0, stream>>>(data_x, gamma, beta, ws, w_t,
                                              b_t, b_s, w_r, b_r, w_g, b_g,
                                              out);
}

// Round 9
// 77.616 us; speedup vs baseline: 2.3174x; 1.0613x over previous
//
#include <hip/hip_runtime.h>

#define Bx 16
#define Cx 64
#define Lx 512
#define Dx 768
#define NPx 68   // int((512+16)/8 + 2)
#define PER 7
#define ROW4 (NPx * (Dx / 4))   // 13056 float4 per (b,c) row
#define HALF4 (ROW4 / 2)        // 6528 (== 0 mod 192)

// ---------------- Kernel A: m[b,l] = mean_c(x) / sqrt(var_c(x, ddof=1)) ----
__global__ void mean_var_kernel(const float* __restrict__ x,
                                float* __restrict__ m) {
    int idx = blockIdx.x * blockDim.x + threadIdx.x;  // b*Lx + l
    if (idx >= Bx * Lx) return;
    int b = idx / Lx, l = idx - b * Lx;
    const float* xp = x + (size_t)b * Cx * Lx + l;
    float s = 0.f, ss = 0.f;
#pragma unroll 8
    for (int c = 0; c < Cx; ++c) {
        float v = xp[(size_t)c * Lx];
        s += v;
        ss += v * v;
    }
    float mean = s / (float)Cx;
    float var = (ss - s * s / (float)Cx) / (float)(Cx - 1);
    m[idx] = mean * rsqrtf(var);
}

// ---------------- Kernel B: per-(b,c) decompose + projections + half-store -
// grid = 2048: blockIdx = bc*2 + h. Both halves compute the same p
// (thread-parallel, so wall-time unchanged); each stores HALF the row.
__global__ __launch_bounds__(256) void token_kernel(
    const float* __restrict__ x, const float* __restrict__ gamma,
    const float* __restrict__ beta, const float* __restrict__ m,
    const float* __restrict__ w_t, const float* __restrict__ b_t,
    const float* __restrict__ w_s, const float* __restrict__ b_s,
    const float* __restrict__ w_r, const float* __restrict__ b_r,
    const float* __restrict__ w_g, const float* __restrict__ b_g,
    float* __restrict__ out) {
    __shared__ __align__(16) float s_xt[Lx];
    __shared__ __align__(16) float s_tr[Lx];
    __shared__ __align__(16) float s_se[Lx];
    __shared__ __align__(16) float s_res[Lx];
    __shared__ float s_ph[PER];
    __shared__ __align__(16) float s_cat[48];
    __shared__ __align__(16) float s_p[Dx];

    const int bc = blockIdx.x >> 1;
    const int h = blockIdx.x & 1;
    const int b = bc >> 6;
    const int tid = threadIdx.x;

    const float* xp = x + (size_t)bc * Lx;
    const float* gp = gamma + (size_t)bc * Lx;
    const float* bp = beta + (size_t)bc * Lx;
    const float* mp = m + (size_t)b * Lx;

    // 1. xt = gamma*(x - m) + beta
    for (int l = tid; l < Lx; l += 256)
        s_xt[l] = gp[l] * (xp[l] - mp[l]) + bp[l];
    __syncthreads();

    // 2. trend = centered 7-pt MA, zero at edges (l in [3, Lx-4] valid)
    for (int l = tid; l < Lx; l += 256) {
        float t = 0.f;
        if (l >= 3 && l <= Lx - 4) {
#pragma unroll
            for (int k = -3; k <= 3; ++k) t += s_xt[l + k];
            t *= (1.f / 7.f);
        }
        s_tr[l] = t;
    }
    __syncthreads();

    // 3. per-phase averages of detrended interior
    if (tid < PER) {
        int p = tid;
        int l0 = p + 7 * ((3 - p + 6) / 7);  // smallest l>=3 with l%7==p
        float sum = 0.f;
        int cnt = 0;
        for (int l = l0; l <= Lx - 4; l += 7) {
            sum += s_xt[l] - s_tr[l];
            ++cnt;
        }
        s_ph[p] = sum / (float)cnt;
    }
    __syncthreads();
    if (tid == 0) {
        float mn = 0.f;
#pragma unroll
        for (int p = 0; p < PER; ++p) mn += s_ph[p];
        mn *= (1.f / 7.f);
#pragma unroll
        for (int p = 0; p < PER; ++p) s_ph[p] -= mn;
    }
    __syncthreads();

    // 4. seasonal (all l) + resid (interior only)
    for (int l = tid; l < Lx; l += 256) {
        float se = s_ph[l % PER];
        s_se[l] = se;
        s_res[l] = (l >= 3 && l <= Lx - 4) ? (s_xt[l] - s_tr[l] - se) : 0.f;
    }
    __syncthreads();

    // 5. cat[48] = [trend@w_t.T+b_t, seasonal@w_s.T+b_s, resid@w_r.T+b_r]
    {
        int j = tid >> 2, q = tid & 3;  // 4 lanes per output, 48 outputs
        if (j < 48) {
            const float* stream;
            const float* w;
            const float* bias;
            int jj;
            if (j < 16) {
                stream = s_tr; w = w_t; bias = b_t; jj = j;
            } else if (j < 32) {
                stream = s_se; w = w_s; bias = b_s; jj = j - 16;
            } else {
                stream = s_res; w = w_r; bias = b_r; jj = j - 32;
            }
            const float4* wr =
                reinterpret_cast<const float4*>(w + (size_t)jj * Lx + q * 128);
            const float4* sp = reinterpret_cast<const float4*>(stream + q * 128);
            float acc = 0.f;
#pragma unroll
            for (int i = 0; i < 32; ++i) {
                float4 a = sp[i], wv = wr[i];
                acc += a.x * wv.x + a.y * wv.y + a.z * wv.z + a.w * wv.w;
            }
            acc += __shfl_xor(acc, 1);
            acc += __shfl_xor(acc, 2);
            if (q == 0) s_cat[j] = acc + bias[jj];
        }
    }
    __syncthreads();

    // 6. p[768] = cat @ w_g.T + b_g
    for (int d = tid; d < Dx; d += 256) {
        const float4* wg4 = reinterpret_cast<const float4*>(w_g + (size_t)d * 48);
        const float4* c4 = reinterpret_cast<const float4*>(s_cat);
        float acc = 0.f;
#pragma unroll
        for (int kk = 0; kk < 12; ++kk) {
            float4 w4 = wg4[kk], cc = c4[kk];
            acc += w4.x * cc.x + w4.y * cc.y + w4.z * cc.z + w4.w * cc.w;
        }
        s_p[d] = acc + b_g[d];
    }
    __syncthreads();

    // 7. store HALF the row (h selects which half); R1's loop-form body.
    //    HALF4 % 192 == 0, so p4 residues are unchanged by the h offset.
    {
        float4* outp = reinterpret_cast<float4*>(out + (size_t)bc * NPx * Dx) +
                       (size_t)h * HALF4;
        const float4* p4 = reinterpret_cast<const float4*>(s_p);
        for (int i = tid; i < HALF4; i += 256) {
            outp[i] = p4[i % 192];
        }
    }
}

extern "C" void kernel_launch(void* const* d_in, const int* in_sizes, int n_in,
                              void* d_out, int out_size, void* d_ws,
                              size_t ws_size, hipStream_t stream) {
    const float* data_x = (const float*)d_in[0];
    // d_in[1] = data_y (unused by the reference)
    const float* gamma = (const float*)d_in[2];
    const float* beta = (const float*)d_in[3];
    const float* w_t = (const float*)d_in[4];
    const float* b_t = (const float*)d_in[5];
    const float* w_s = (const float*)d_in[6];
    const float* b_s = (const float*)d_in[7];
    const float* w_r = (const float*)d_in[8];
    const float* b_r = (const float*)d_in[9];
    const float* w_g = (const float*)d_in[10];
    const float* b_g = (const float*)d_in[11];
    float* out = (float*)d_out;
    float* m = (float*)d_ws;  // B*L floats = 32 KB

    int nthreads_m = Bx * Lx;
    mean_var_kernel<<<(nthreads_m + 255) / 256, 256, 0, stream>>>(data_x, m);

    token_kernel<<<2 * Bx * Cx, 256, 0, stream>>>(data_x, gamma, beta, m, w_t,
                                                  b_t, w_s, b_s, w_r, b_r, w_g,
                                                  b_g, out);
}